// Round 5
// baseline (101.688 us; speedup 1.0000x reference)
//
#include <hip/hip_runtime.h>
#include <stdint.h>

// QuadraticConv2DTranspose, stride 2, k=3 — single-kernel bf16 MFMA GEMM.
// Bed-of-nails upsample => per output parity class only 2/5/5/14 of the 55
// features are live (+ pixel-independent bias). Per class:
//   out[m,n] = bias[n] + sum_k F[m,k] * W[k,n],  k = f*64 + c.
// Round 5: ONE dispatch total (rounds 2-4 showed the measured window is
// dominated by harness fills/dispatch overhead; minimize our dispatches).
// Bias computed inline per block; W staged per feature (full k=64) from the
// original [l][c][n] layout into bf16 B-fragment LDS layout, double-buffered
// -> NF barriers per block (round 2 had 2*NF). A-frags built in registers
// from an x-tile staged once.

typedef __attribute__((ext_vector_type(8))) short short8;
typedef __attribute__((ext_vector_type(4))) float floatx4;

// Pack bf16(a) (low) | bf16(b) (high), round-half-up: 2 adds + 1 v_perm.
__device__ __forceinline__ uint32_t pk2bf(float a, float b) {
  union { float f; uint32_t u; } x{a}, y{b};
  return __builtin_amdgcn_perm(y.u + 0x8000u, x.u + 0x8000u, 0x07060302u);
}

// Per-class tables. Patch value j = x[hi+DY[j], wi+DX[j]].
// Feature f: kernel row L[f], value v[A[f]]*v[Bb[f]]; Bb[f]==NV -> linear.
template <int CLS> struct CI;
template <> struct CI<0> {  // ho even, wo even
  static constexpr int NV = 1, NF = 2;
  static constexpr int L[NF] = {30, 49};
  static constexpr int A[NF] = {0, 0};
  static constexpr int Bb[NF] = {0, 1};
  static constexpr int DY[NV] = {0};
  static constexpr int DX[NV] = {0};
};
template <> struct CI<1> {  // ho even, wo odd
  static constexpr int NV = 2, NF = 5;
  static constexpr int L[NF] = {24, 26, 35, 48, 50};
  static constexpr int A[NF] = {0, 0, 1, 0, 1};
  static constexpr int Bb[NF] = {0, 1, 1, 2, 2};
  static constexpr int DY[NV] = {0, 0};
  static constexpr int DX[NV] = {0, 1};
};
template <> struct CI<2> {  // ho odd, wo even
  static constexpr int NV = 2, NF = 5;
  static constexpr int L[NF] = {9, 15, 42, 46, 52};
  static constexpr int A[NF] = {0, 0, 1, 0, 1};
  static constexpr int Bb[NF] = {0, 1, 1, 2, 2};
  static constexpr int DY[NV] = {0, 1};
  static constexpr int DX[NV] = {0, 0};
};
template <> struct CI<3> {  // ho odd, wo odd
  static constexpr int NV = 4, NF = 14;
  static constexpr int L[NF] = {0, 2, 6, 8, 17, 21, 23, 39, 41, 44, 45, 47, 51, 53};
  static constexpr int A[NF] = {0, 0, 0, 0, 1, 1, 1, 2, 2, 3, 0, 1, 2, 3};
  static constexpr int Bb[NF] = {0, 1, 2, 3, 1, 2, 3, 2, 3, 3, 4, 4, 4, 4};
  static constexpr int DY[NV] = {0, 0, 1, 1};
  static constexpr int DX[NV] = {0, 1, 0, 1};
};

template <int CLS>
__device__ __forceinline__ void body(const float* __restrict__ x,
                                     const float* __restrict__ kern,
                                     float* __restrict__ out, int b, int hi0,
                                     int wi0, float (&sX)[45][68],
                                     short (&sB)[2][64][72],
                                     float (&sbias)[4][64]) {
  using I = CI<CLS>;
  constexpr int NV = I::NV, NF = I::NF;
  const int tid = threadIdx.x;
  const int wave = tid >> 6, lane = tid & 63;
  const int quad = lane >> 4, l16 = lane & 15;
  const int mb = (wave & 1) * 16;   // wave's m-block (pixels)
  const int nh = (wave >> 1) * 32;  // wave's n-half (couts)
  const int m = mb + l16;           // A row (m = lane&15)
  const int ph = m >> 3, pw = m & 7;
  const int c8 = quad * 8;          // k-offset within 32-chunk (quad*8+j)
  const int sn = lane;              // staging: this lane's cout column
  const int skb = wave * 16;        // staging: this wave's k-base

  // Inline bias partials: wave sums 16 channels of kern row 54 for column sn.
  {
    float s = 0.f;
    const float* bp = &kern[(54 * 64 + wave * 16) * 64 + sn];
#pragma unroll
    for (int c = 0; c < 16; ++c) s += bp[c * 64];
    sbias[wave][sn] = s;  // bank = sn%32 -> 2-way, free
  }

  // Stage x tile once: 5x9 positions x 64 ch fp32, zero OOB (boundary
  // handling for free). Row stride 68 floats -> b128 reads 2-way (free).
  for (int i = tid; i < 720; i += 256) {
    const int pos = i >> 4, c4 = (i & 15) * 4;
    const int hr = hi0 + pos / 9, wc = wi0 + pos % 9;
    float4 v = make_float4(0.f, 0.f, 0.f, 0.f);
    if (hr < 32 && wc < 32)
      v = *(const float4*)&x[(((b * 32) + hr) * 32 + wc) * 64 + c4];
    *(float4*)&sX[pos][c4] = v;
  }
  __syncthreads();

  // Cache this lane's patch planes: 16 channels (8 per k-half) x NV values.
  float vpl[NV][16];
#pragma unroll
  for (int j = 0; j < NV; ++j) {
    const int pa = (ph + I::DY[j]) * 9 + (pw + I::DX[j]);
    *(float4*)&vpl[j][0] = *(const float4*)&sX[pa][c8];
    *(float4*)&vpl[j][4] = *(const float4*)&sX[pa][c8 + 4];
    *(float4*)&vpl[j][8] = *(const float4*)&sX[pa][32 + c8];
    *(float4*)&vpl[j][12] = *(const float4*)&sX[pa][32 + c8 + 4];
  }

  floatx4 acc[2];
#pragma unroll
  for (int nt = 0; nt < 2; ++nt) {  // C/D col = n -> same bias for all rows
    const int n = nh + nt * 16 + l16;
    const float bv = sbias[0][n] + sbias[1][n] + sbias[2][n] + sbias[3][n];
    acc[nt] = floatx4{bv, bv, bv, bv};
  }

  // Feature loop: stage W[l][*][*] (full k=64) -> sB[f&1][n][k] bf16, one
  // barrier per feature (dbuf; read(f) < stage(f+1) < bar(f+1) < stage(f+2)
  // in every wave's program order => single barrier is race-free).
#pragma unroll 1
  for (int f = 0; f < NF; ++f) {
    short(&B)[64][72] = sB[f & 1];
    {
      const float* src = &kern[(I::L[f] * 64 + skb) * 64 + sn];
      float w[16];
#pragma unroll
      for (int j = 0; j < 16; ++j) w[j] = src[j * 64];  // coalesced 256B rows
      union { uint32_t d[8]; short8 s[2]; } u;
#pragma unroll
      for (int h = 0; h < 8; ++h) u.d[h] = pk2bf(w[2 * h], w[2 * h + 1]);
      *(short8*)&B[sn][skb] = u.s[0];
      *(short8*)&B[sn][skb + 8] = u.s[1];
    }
    __syncthreads();
    // A-frags for both k-halves from cached planes (zero LDS traffic).
    short8 af[2];
#pragma unroll
    for (int ch = 0; ch < 2; ++ch) {
      union { uint32_t d[4]; short8 s; } ua;
#pragma unroll
      for (int h = 0; h < 4; ++h) {
        const int j0 = ch * 8 + 2 * h, j1 = j0 + 1;
        float a0 = vpl[I::A[f]][j0], a1 = vpl[I::A[f]][j1];
        if (I::Bb[f] != NV) { a0 *= vpl[I::Bb[f]][j0]; a1 *= vpl[I::Bb[f]][j1]; }
        ua.d[h] = pk2bf(a0, a1);
      }
      af[ch] = ua.s;
    }
#pragma unroll
    for (int nt = 0; nt < 2; ++nt) {
      const int n = nh + nt * 16 + l16;
      // row stride 72 shorts = 144B: 16B-aligned frags, reads 2-way (free)
      const short8 b0 = *(const short8*)&B[n][c8];
      const short8 b1 = *(const short8*)&B[n][32 + c8];
      acc[nt] = __builtin_amdgcn_mfma_f32_16x16x32_bf16(af[0], b0, acc[nt], 0, 0, 0);
      acc[nt] = __builtin_amdgcn_mfma_f32_16x16x32_bf16(af[1], b1, acc[nt], 0, 0, 0);
    }
  }

  // Epilogue. D: col = n (lane&15 group), row = quad*4 + reg.
  constexpr int rh = CLS >> 1, rw = CLS & 1;
#pragma unroll
  for (int nt = 0; nt < 2; ++nt) {
    const int n = nh + nt * 16 + l16;
#pragma unroll
    for (int r = 0; r < 4; ++r) {
      const int mm = mb + quad * 4 + r;
      const int hi = hi0 + (mm >> 3), wi = wi0 + (mm & 7);
      const int ho = 2 * hi + rh, wo = 2 * wi + rw;
      out[(((b * 64) + ho) * 64 + wo) * 64 + n] = acc[nt][r];
    }
  }
}

__global__ __launch_bounds__(256) void qct_main(const float* __restrict__ x,
                                                const float* __restrict__ kern,
                                                float* __restrict__ out) {
  __shared__ float sX[45][68];                       // 12.2 KB
  __shared__ __align__(16) short sB[2][64][72];      // 18.4 KB (W dbuf)
  __shared__ float sbias[4][64];                     // 1 KB
  const int bid = blockIdx.x;
  // OO first: longest-job-first across CUs (7:1 per-class work ratio).
  int cls, blk;
  if (bid < 256)      { cls = 3; blk = bid; }
  else if (bid < 512) { cls = 1; blk = bid - 256; }
  else if (bid < 768) { cls = 2; blk = bid - 512; }
  else                { cls = 0; blk = bid - 768; }
  const int b = blk >> 5, tile = blk & 31;
  const int hi0 = (tile >> 2) * 4;  // 4x8 class-space tile = 32 pixels
  const int wi0 = (tile & 3) * 8;
  switch (cls) {
    case 0: body<0>(x, kern, out, b, hi0, wi0, sX, sB, sbias); break;
    case 1: body<1>(x, kern, out, b, hi0, wi0, sX, sB, sbias); break;
    case 2: body<2>(x, kern, out, b, hi0, wi0, sX, sB, sbias); break;
    case 3: body<3>(x, kern, out, b, hi0, wi0, sX, sB, sbias); break;
  }
}

extern "C" void kernel_launch(void* const* d_in, const int* in_sizes, int n_in,
                              void* d_out, int out_size, void* d_ws,
                              size_t ws_size, hipStream_t stream) {
  const float* x = (const float*)d_in[0];     // [8,32,32,64] f32
  const float* kern = (const float*)d_in[1];  // [55,64,64]   f32
  float* out = (float*)d_out;                 // [8,64,64,64] f32
  (void)d_ws; (void)ws_size;
  // Single dispatch: 1024 blocks x 256 thr, ~31 KB LDS -> 5 blocks/CU
  // (20 waves/CU hides the per-feature stage latency chain).
  qct_main<<<1024, 256, 0, stream>>>(x, kern, out);
}

// Round 6
// 74.398 us; speedup vs baseline: 1.3668x; 1.3668x over previous
//
#include <hip/hip_runtime.h>
#include <stdint.h>

// QuadraticConv2DTranspose via per-parity-class bf16 MFMA GEMM.
// Bed-of-nails stride-2 upsample => per output parity class only 2/5/5/14 of
// the 55 features are live (+ pixel-independent bias vector).
//   out[m,n] = bias[n] + sum_k F[m,k] * W[k,n],  k = f*64 + c
// Round 6 = round 3 (prep_w pre-transposes W to bf16 frag layout; K-loop has
// data-independent B-frag loads, one barrier) + LDS epilogue transpose:
// round-5 counters showed the MFMA-layout dword-scatter epilogue costs
// 46 MB HBM writes for an 8.4 MB output (partial 64B segments -> RMW);
// round-1's full-line float4 epilogue measured exactly 8.4 MB. Rebuild
// full-line stores by bouncing acc through LDS.

typedef __attribute__((ext_vector_type(8))) short short8;
typedef __attribute__((ext_vector_type(4))) short short4v;
typedef __attribute__((ext_vector_type(4))) float floatx4;

__device__ __forceinline__ short f2bf(float f) {  // RTN-even fp32->bf16
  union { float f; uint32_t u; } v{f};
  uint32_t u = v.u;
  u += 0x7fffu + ((u >> 16) & 1u);
  return (short)(u >> 16);
}

// Pack bf16(a) (low) | bf16(b) (high), round-half-up: 2 adds + 1 v_perm.
__device__ __forceinline__ uint32_t pk2bf(float a, float b) {
  union { float f; uint32_t u; } x{a}, y{b};
  return __builtin_amdgcn_perm(y.u + 0x8000u, x.u + 0x8000u, 0x07060302u);
}

// Per-class tables. Patch value j = x[hi+DY[j], wi+DX[j]].
// Feature f: kernel row L[f], value v[A[f]]*v[Bb[f]]; Bb[f]==NV -> linear.
template <int CLS> struct CI;
template <> struct CI<0> {  // ho even, wo even
  static constexpr int NV = 1, NF = 2;
  static constexpr int L[NF] = {30, 49};
  static constexpr int A[NF] = {0, 0};
  static constexpr int Bb[NF] = {0, 1};
  static constexpr int DY[NV] = {0};
  static constexpr int DX[NV] = {0};
};
template <> struct CI<1> {  // ho even, wo odd
  static constexpr int NV = 2, NF = 5;
  static constexpr int L[NF] = {24, 26, 35, 48, 50};
  static constexpr int A[NF] = {0, 0, 1, 0, 1};
  static constexpr int Bb[NF] = {0, 1, 1, 2, 2};
  static constexpr int DY[NV] = {0, 0};
  static constexpr int DX[NV] = {0, 1};
};
template <> struct CI<2> {  // ho odd, wo even
  static constexpr int NV = 2, NF = 5;
  static constexpr int L[NF] = {9, 15, 42, 46, 52};
  static constexpr int A[NF] = {0, 0, 1, 0, 1};
  static constexpr int Bb[NF] = {0, 1, 1, 2, 2};
  static constexpr int DY[NV] = {0, 1};
  static constexpr int DX[NV] = {0, 0};
};
template <> struct CI<3> {  // ho odd, wo odd
  static constexpr int NV = 4, NF = 14;
  static constexpr int L[NF] = {0, 2, 6, 8, 17, 21, 23, 39, 41, 44, 45, 47, 51, 53};
  static constexpr int A[NF] = {0, 0, 0, 0, 1, 1, 1, 2, 2, 3, 0, 1, 2, 3};
  static constexpr int Bb[NF] = {0, 1, 2, 3, 1, 2, 3, 2, 3, 3, 4, 4, 4, 4};
  static constexpr int DY[NV] = {0, 0, 1, 1};
  static constexpr int DX[NV] = {0, 1, 0, 1};
};

// Prologue: wt[(l*64+n)*64+c] = bf16(kern[(l*64+c)*64+n]); block 54 also
// reduces bias[n] = sum_c kern[54][c][n].
__global__ __launch_bounds__(256) void prep_w(const float* __restrict__ kern,
                                              short* __restrict__ wt,
                                              float* __restrict__ bias) {
  __shared__ float s[64][65];
  const int l = blockIdx.x;
  const int tid = threadIdx.x;
  for (int i = tid; i < 4096; i += 256)
    s[i >> 6][i & 63] = kern[(l << 12) + i];
  __syncthreads();
  if (l == 54 && tid < 64) {
    float a = 0.f;
    for (int c = 0; c < 64; ++c) a += s[c][tid];
    bias[tid] = a;
  }
  for (int i = tid; i < 1024; i += 256) {
    const int n = i >> 4, c4 = (i & 15) * 4;
    short4v v;
    v[0] = f2bf(s[c4 + 0][n]);
    v[1] = f2bf(s[c4 + 1][n]);
    v[2] = f2bf(s[c4 + 2][n]);
    v[3] = f2bf(s[c4 + 3][n]);
    *(short4v*)&wt[((l << 6) + n) * 64 + c4] = v;
  }
}

template <int CLS>
__device__ __forceinline__ void body(const float* __restrict__ x,
                                     const short* __restrict__ wt,
                                     const float* __restrict__ bias,
                                     float* __restrict__ out, int b, int hi0,
                                     int wi0, float* __restrict__ smem) {
  using I = CI<CLS>;
  constexpr int NV = I::NV, NF = I::NF;
  const int tid = threadIdx.x;
  const int wave = tid >> 6, lane = tid & 63;
  const int quad = lane >> 4, l16 = lane & 15;
  const int mb = (wave & 1) * 16;   // wave's m-block (pixels)
  const int nh = (wave >> 1) * 32;  // wave's n-half (couts)
  const int m = mb + l16;           // A row (m = lane&15)
  const int ph = m >> 3, pw = m & 7;
  const int c8 = quad * 8;          // k-offset within 32-chunk (quad*8+j)

  // Phase 1: smem = sX[45][68] fp32 x-tile (5x9 positions x 64 ch, zero
  // OOB -> boundaries for free; stride 68 -> b128 2-way only, free).
  for (int i = tid; i < 720; i += 256) {
    const int pos = i >> 4, c4 = (i & 15) * 4;
    const int hr = hi0 + pos / 9, wc = wi0 + pos % 9;
    float4 v = make_float4(0.f, 0.f, 0.f, 0.f);
    if (hr < 32 && wc < 32)
      v = *(const float4*)&x[(((b * 32) + hr) * 32 + wc) * 64 + c4];
    *(float4*)&smem[pos * 68 + c4] = v;
  }

  floatx4 acc[2];
#pragma unroll
  for (int nt = 0; nt < 2; ++nt) {  // C/D col = n -> same bias for all rows
    const float bv = bias[nh + nt * 16 + l16];
    acc[nt] = floatx4{bv, bv, bv, bv};
  }

  __syncthreads();

  // Cache this lane's patch planes: 16 channels (8 per k-half) x NV values.
  float vpl[NV][16];
#pragma unroll
  for (int j = 0; j < NV; ++j) {
    const int pa = ((ph + I::DY[j]) * 9 + (pw + I::DX[j])) * 68;
    *(float4*)&vpl[j][0] = *(const float4*)&smem[pa + c8];
    *(float4*)&vpl[j][4] = *(const float4*)&smem[pa + c8 + 4];
    *(float4*)&vpl[j][8] = *(const float4*)&smem[pa + 32 + c8];
    *(float4*)&vpl[j][12] = *(const float4*)&smem[pa + 32 + c8 + 4];
  }

#pragma unroll
  for (int chalf = 0; chalf < 2; ++chalf) {
#pragma unroll
    for (int f = 0; f < NF; ++f) {
      // B-frags: data-independent addresses -> compiler pipelines freely;
      // wt row is exactly the fragment layout (k contiguous per n).
      const short* wr = wt + (I::L[f] * 64) * 64 + chalf * 32 + c8;
      const short8 b0 = *(const short8*)&wr[(nh + l16) * 64];
      const short8 b1 = *(const short8*)&wr[(nh + 16 + l16) * 64];
      short8 af;
      {
        union { uint32_t d[4]; short8 s; } ua;
#pragma unroll
        for (int h = 0; h < 4; ++h) {
          const int j0 = chalf * 8 + 2 * h, j1 = j0 + 1;
          float a0 = vpl[I::A[f]][j0], a1 = vpl[I::A[f]][j1];
          if (I::Bb[f] != NV) { a0 *= vpl[I::Bb[f]][j0]; a1 *= vpl[I::Bb[f]][j1]; }
          ua.d[h] = pk2bf(a0, a1);
        }
        af = ua.s;
      }
      acc[0] = __builtin_amdgcn_mfma_f32_16x16x32_bf16(af, b0, acc[0], 0, 0, 0);
      acc[1] = __builtin_amdgcn_mfma_f32_16x16x32_bf16(af, b1, acc[1], 0, 0, 0);
    }
  }

  // Phase 2: epilogue transpose through LDS -> full-line global stores.
  // Round-5 counters: dword-scatter epilogue = 46 MB HBM writes for 8.4 MB
  // of output (partial 64B segments); full 256B/pixel float4 stores = 8.4 MB.
  __syncthreads();  // all vpl reads done before overwriting smem
#pragma unroll
  for (int nt = 0; nt < 2; ++nt)
#pragma unroll
    for (int r = 0; r < 4; ++r)  // sO[pixel][n], stride 68
      smem[(mb + quad * 4 + r) * 68 + nh + nt * 16 + l16] = acc[nt][r];
  __syncthreads();

  constexpr int rh = CLS >> 1, rw = CLS & 1;
  for (int i = tid; i < 512; i += 256) {
    const int p = i >> 4, ng = (i & 15) * 4;
    const float4 v = *(const float4*)&smem[p * 68 + ng];
    const int hi = hi0 + (p >> 3), wi = wi0 + (p & 7);
    const int ho = 2 * hi + rh, wo = 2 * wi + rw;
    // 16-lane group writes one pixel's 256 B contiguously (2 full lines).
    *(float4*)&out[(((b * 64) + ho) * 64 + wo) * 64 + ng] = v;
  }
}

__global__ __launch_bounds__(256, 4) void qct_main(const float* __restrict__ x,
                                                   const short* __restrict__ wt,
                                                   const float* __restrict__ bias,
                                                   float* __restrict__ out) {
  __shared__ __align__(16) float smem[45 * 68];  // 12.2 KB: sX, then sO[32][68]
  const int bid = blockIdx.x;
  // OO first: longest-job-first across CUs (7:1 per-class work ratio).
  int cls, blk;
  if (bid < 256)      { cls = 3; blk = bid; }
  else if (bid < 512) { cls = 1; blk = bid - 256; }
  else if (bid < 768) { cls = 2; blk = bid - 512; }
  else                { cls = 0; blk = bid - 768; }
  const int b = blk >> 5, tile = blk & 31;
  const int hi0 = (tile >> 2) * 4;  // 4x8 class-space tile = 32 pixels
  const int wi0 = (tile & 3) * 8;
  switch (cls) {
    case 0: body<0>(x, wt, bias, out, b, hi0, wi0, smem); break;
    case 1: body<1>(x, wt, bias, out, b, hi0, wi0, smem); break;
    case 2: body<2>(x, wt, bias, out, b, hi0, wi0, smem); break;
    case 3: body<3>(x, wt, bias, out, b, hi0, wi0, smem); break;
  }
}

extern "C" void kernel_launch(void* const* d_in, const int* in_sizes, int n_in,
                              void* d_out, int out_size, void* d_ws,
                              size_t ws_size, hipStream_t stream) {
  const float* x = (const float*)d_in[0];     // [8,32,32,64] f32
  const float* kern = (const float*)d_in[1];  // [55,64,64]   f32
  float* out = (float*)d_out;                 // [8,64,64,64] f32
  short* wt = (short*)d_ws;                   // 55*64*64 bf16
  float* bias = (float*)((char*)d_ws + 55 * 64 * 64 * 2);

  prep_w<<<55, 256, 0, stream>>>(kern, wt, bias);
  qct_main<<<1024, 256, 0, stream>>>(x, wt, bias, out);
}

// Round 7
// 74.032 us; speedup vs baseline: 1.3736x; 1.0049x over previous
//
#include <hip/hip_runtime.h>
#include <stdint.h>

// QuadraticConv2DTranspose, stride 2, k=3 — fused-class bf16 MFMA GEMM.
// Bed-of-nails upsample => the 4 output parity classes (EE,EO,OE,OO) have
// 2/5/5/14 live features of the 55, all products of the same 2x2 input
// window (+ pixel-independent bias). Round 7 = round 4's class fusion
// (x-tile staged ONCE, 14 shared bf16 products, 52 interleaved MFMA steps)
// + round 6's LDS epilogue transpose (full-line stores; round 5 counters
// showed the C-layout dword scatter writes 46 MB HBM for an 8.4 MB output).
// W pre-transposed once to bf16 fragment layout wt[l][n][c] by prep_w.

typedef __attribute__((ext_vector_type(8))) short short8;
typedef __attribute__((ext_vector_type(4))) short short4v;
typedef __attribute__((ext_vector_type(4))) float floatx4;

__device__ __forceinline__ short f2bf(float f) {  // RTN-even fp32->bf16
  union { float f; uint32_t u; } v{f};
  uint32_t u = v.u;
  u += 0x7fffu + ((u >> 16) & 1u);
  return (short)(u >> 16);
}

// Pack bf16(a) (low) | bf16(b) (high), round-half-up: 2 adds + 1 v_perm.
__device__ __forceinline__ uint32_t pk2bf(float a, float b) {
  union { float f; uint32_t u; } x{a}, y{b};
  return __builtin_amdgcn_perm(y.u + 0x8000u, x.u + 0x8000u, 0x07060302u);
}

// 14 distinct products over window values w0=(0,0) w1=(0,1) w2=(1,0) w3=(1,1):
// p0..p9 = upper-tri pairs, p10..p13 = linear.
__constant__ __device__ const int cQA[10] = {0, 0, 0, 0, 1, 1, 1, 2, 2, 3};
__constant__ __device__ const int cQB[10] = {0, 1, 2, 3, 1, 2, 3, 2, 3, 3};
// 26 (product, class, kernel-row) steps; class bit1 = ho parity, bit0 = wo.
// Product-major order interleaves the 4 acc chains (hides MFMA latency).
__constant__ __device__ const int cPP[26] = {0, 0, 0, 0, 1, 1, 2, 2, 3, 4, 4, 5, 6,
                                             7, 7, 8, 9, 10, 10, 10, 10, 11, 11, 12, 12, 13};
__constant__ __device__ const int cPC[26] = {0, 1, 2, 3, 1, 3, 2, 3, 3, 1, 3, 3, 3,
                                             2, 3, 3, 3, 0, 1, 2, 3, 1, 3, 2, 3, 3};
__constant__ __device__ const int cPL[26] = {30, 24, 9, 0, 26, 2, 15, 6, 8, 35, 17, 21, 23,
                                             42, 39, 41, 44, 49, 48, 46, 45, 50, 47, 52, 51, 53};

// Prologue: wt[(l*64+n)*64+c] = bf16(kern[(l*64+c)*64+n]); block 54 also
// reduces bias[n] = sum_c kern[54][c][n].
__global__ __launch_bounds__(256) void prep_w(const float* __restrict__ kern,
                                              short* __restrict__ wt,
                                              float* __restrict__ bias) {
  __shared__ float s[64][65];
  const int l = blockIdx.x;
  const int tid = threadIdx.x;
  for (int i = tid; i < 4096; i += 256)
    s[i >> 6][i & 63] = kern[(l << 12) + i];
  __syncthreads();
  if (l == 54 && tid < 64) {
    float a = 0.f;
    for (int c = 0; c < 64; ++c) a += s[c][tid];
    bias[tid] = a;
  }
  for (int i = tid; i < 1024; i += 256) {
    const int n = i >> 4, c4 = (i & 15) * 4;
    short4v v;
    v[0] = f2bf(s[c4 + 0][n]);
    v[1] = f2bf(s[c4 + 1][n]);
    v[2] = f2bf(s[c4 + 2][n]);
    v[3] = f2bf(s[c4 + 3][n]);
    *(short4v*)&wt[((l << 6) + n) * 64 + c4] = v;
  }
}

__global__ __launch_bounds__(512, 2) void qct_main(const float* __restrict__ x,
                                                   const short* __restrict__ wt,
                                                   const float* __restrict__ bias,
                                                   float* __restrict__ out) {
  // sX[45][68] fp32 x-tile; epilogue reuses the same buffer as sO[32][68].
  __shared__ __align__(16) float smem[45 * 68];  // 12.2 KB
  const int tid = threadIdx.x;
  const int bid = blockIdx.x;
  const int b = bid >> 5, tile = bid & 31;
  const int hi0 = (tile >> 2) * 4;  // 4x8 input-pixel tile (+1 halo = 5x9)
  const int wi0 = (tile & 3) * 8;

  // Stage x tile ONCE for all 4 classes (zero-fill OOB -> boundary-free).
  for (int i = tid; i < 720; i += 512) {
    const int pos = i >> 4, c4 = (i & 15) * 4;
    const int hr = hi0 + pos / 9, wc = wi0 + pos % 9;
    float4 v = make_float4(0.f, 0.f, 0.f, 0.f);
    if (hr < 32 && wc < 32)
      v = *(const float4*)&x[(((b * 32) + hr) * 32 + wc) * 64 + c4];
    *(float4*)&smem[pos * 68 + c4] = v;
  }

  const int wave = tid >> 6, lane = tid & 63;
  const int quad = lane >> 4, l16 = lane & 15;
  const int mh = wave >> 2;  // m-half: pixels mh*16.. (twin waves share B -> L1)
  const int nt = wave & 3;   // n-tile of 16 couts
  const int n = nt * 16 + l16;
  const int p = mh * 16 + l16;        // this lane's A-row pixel
  const int ph = p >> 3, pw = p & 7;  // position in 4x8 tile
  const int c8 = quad * 8;            // k-offset: k = quad*8 + j

  floatx4 acc[4];
  {
    const float bv = bias[n];  // C/D col = n for all rows
    acc[0] = acc[1] = acc[2] = acc[3] = floatx4{bv, bv, bv, bv};
  }

  __syncthreads();

#pragma unroll
  for (int chalf = 0; chalf < 2; ++chalf) {
    const int cb = chalf * 32 + c8;
    // 2x2 window values, 8 channels each (from LDS; stride 68 -> 2-way, free).
    float v[4][8];
#pragma unroll
    for (int dy = 0; dy < 2; ++dy)
#pragma unroll
      for (int dx = 0; dx < 2; ++dx) {
        const int pa = ((ph + dy) * 9 + (pw + dx)) * 68;
        *(float4*)&v[dy * 2 + dx][0] = *(const float4*)&smem[pa + cb];
        *(float4*)&v[dy * 2 + dx][4] = *(const float4*)&smem[pa + cb + 4];
      }
    // 14 shared bf16 A-frag products, built once for all 4 classes.
    short8 pr[14];
#pragma unroll
    for (int q = 0; q < 10; ++q) {
      union { uint32_t w[4]; short8 s; } u;
#pragma unroll
      for (int h = 0; h < 4; ++h)
        u.w[h] = pk2bf(v[cQA[q]][2 * h] * v[cQB[q]][2 * h],
                       v[cQA[q]][2 * h + 1] * v[cQB[q]][2 * h + 1]);
      pr[q] = u.s;
    }
#pragma unroll
    for (int t = 0; t < 4; ++t) {
      union { uint32_t w[4]; short8 s; } u;
#pragma unroll
      for (int h = 0; h < 4; ++h)
        u.w[h] = pk2bf(v[t][2 * h], v[t][2 * h + 1]);
      pr[10 + t] = u.s;
    }
    // 26 MFMA steps; wt row is exactly the B-fragment layout; addresses are
    // data-independent -> fully pipelined, no barriers.
#pragma unroll
    for (int s = 0; s < 26; ++s) {
      const short8 bf =
          *(const short8*)&wt[((cPL[s] * 64) + n) * 64 + chalf * 32 + c8];
      acc[cPC[s]] =
          __builtin_amdgcn_mfma_f32_16x16x32_bf16(pr[cPP[s]], bf, acc[cPC[s]], 0, 0, 0);
    }
  }

  // Epilogue: per class, bounce acc through LDS (reusing smem as sO[32][68])
  // so every global store is a full-line 256 B/pixel float4 burst.
#pragma unroll
  for (int cls = 0; cls < 4; ++cls) {
    const int rh = cls >> 1, rw = cls & 1;
    __syncthreads();  // cls=0: also orders last sX reads before overwrite
#pragma unroll
    for (int r = 0; r < 4; ++r)  // D row = quad*4+r, col = n
      smem[(mh * 16 + quad * 4 + r) * 68 + n] = acc[cls][r];
    __syncthreads();
    const int pp = tid >> 4, ng = (tid & 15) * 4;  // 512 thr = 32 px x 16 grp
    const float4 o = *(const float4*)&smem[pp * 68 + ng];
    const int hi = hi0 + (pp >> 3), wi = wi0 + (pp & 7);
    const int ho = 2 * hi + rh, wo = 2 * wi + rw;
    *(float4*)&out[(((b * 64) + ho) * 64 + wo) * 64 + ng] = o;
  }
}

extern "C" void kernel_launch(void* const* d_in, const int* in_sizes, int n_in,
                              void* d_out, int out_size, void* d_ws,
                              size_t ws_size, hipStream_t stream) {
  const float* x = (const float*)d_in[0];     // [8,32,32,64] f32
  const float* kern = (const float*)d_in[1];  // [55,64,64]   f32
  float* out = (float*)d_out;                 // [8,64,64,64] f32
  short* wt = (short*)d_ws;                   // 55*64*64 bf16
  float* bias = (float*)((char*)d_ws + 55 * 64 * 64 * 2);

  prep_w<<<55, 256, 0, stream>>>(kern, wt, bias);
  // 256 blocks x 512 threads: uniform per-block work (all classes fused),
  // single generation, x fetched once per tile instead of 4x.
  qct_main<<<256, 512, 0, stream>>>(x, wt, bias, out);
}